// Round 5
// baseline (675.940 us; speedup 1.0000x reference)
//
#include <hip/hip_runtime.h>
#include <stdint.h>

#define LM1  127
#define NTHR 1024

typedef _Float16 half8_t __attribute__((ext_vector_type(8)));
typedef float    f32x4   __attribute__((ext_vector_type(4)));

__device__ __forceinline__ float fast_tanh(float x) {
  float e = __expf(2.0f * x);
  return 1.0f - 2.0f * __builtin_amdgcn_rcpf(e + 1.0f);
}

// 256 blocks x 4 rows x 16 waves. MFMA 16x16x32 f16, weights in registers.
// LDS-diet version: A-fragment reads exec-masked to the 4 real rows
// (zero-init regs carry rows 4..15), zsb/hA shrunk to 4-row chunk layouts,
// dXdt g-values live in per-lane registers (global L2 prefetch, no LDS).
// Per-CU LDS-pipe budget/sub-stage ~950 cyc (was ~2400 = the R4 ceiling).
__global__ void __launch_bounds__(NTHR, 4) cde_kernel(
    const float* __restrict__ coeffs,
    const float* __restrict__ Wi1, const float* __restrict__ bi1,
    const float* __restrict__ Wi2, const float* __restrict__ bi2,
    const float* __restrict__ W1,  const float* __restrict__ b1,
    const float* __restrict__ W2,  const float* __restrict__ b2,
    float* __restrict__ out)
{
  __shared__ _Float16 zsb[256];     // [kh2][lq4][m4][j8]: idx=kh*128+lq*32+m*8+j
  __shared__ _Float16 hA [512];     // [kt4][lq4][m4][j8]: idx=kt*128+lq*32+m*8+j
  __shared__ float    fwb[16][144]; // per-wave D: word = 36*(cl>>3)+4*(cl&7)+r

  const int t    = threadIdx.x;
  const int lane = t & 63;
  const int w    = t >> 6;            // wave 0..15
  const int l15  = lane & 15;
  const int lq   = lane >> 4;         // quad 0..3
  const int r    = lane & 3;
  const int row0 = blockIdx.x * 4;

  // ---- W1 -> B-fragments (waves 0..7) + epilogue constants
  half8_t bB[2] = {};
  float w1t_c = 0.f, b1_c = 0.f;
  if (w < 8) {
    #pragma unroll
    for (int kt = 0; kt < 2; ++kt)
      #pragma unroll
      for (int j = 0; j < 8; ++j)
        bB[kt][j] = (_Float16)W1[(1 + kt * 32 + lq * 8 + j) * 128 + w * 16 + l15];
    w1t_c = W1[w * 16 + l15];
    b1_c  = b1[w * 16 + l15];
  }

  // ---- W2 -> B-fragments: 2 n-tiles x 4 k-tiles (cols 32w + nt*16 + l15)
  half8_t bf[2][4];
  #pragma unroll
  for (int nt = 0; nt < 2; ++nt)
    #pragma unroll
    for (int kt = 0; kt < 4; ++kt)
      #pragma unroll
      for (int j = 0; j < 8; ++j)
        bf[nt][kt][j] =
            (_Float16)W2[(kt * 32 + lq * 8 + j) * 512 + w * 32 + nt * 16 + l15];

  // ---- kc constants: lane = q*16 + hxl*4 + r, channels 2q, 2q+1
  const int q    = lane >> 4;
  const int hxl  = (lane >> 2) & 3;
  const int hxk  = w * 4 + hxl;
  const float b2r0 = b2[hxk * 8 + 2 * q];
  const float b2r1 = b2[hxk * 8 + 2 * q + 1];

  // ---- owner constants (lanes 0..15): r = lane&3, hxo = w*4 + (lane>>2)
  const int hxo = w * 4 + (lane >> 2);
  _Float16* const zwp = &zsb[(hxo >> 5) * 128 + ((hxo >> 3) & 3) * 32 + r * 8 + (hxo & 7)];
  _Float16* hwp;                      // phase-B h write base (w<8, lane<16)
  {
    const int col = 16 * w + l15;
    hwp = &hA[((col >> 5) & 3) * 128 + ((col >> 3) & 3) * 32 + (col & 7)];
  }
  float* const fsp = &fwb[w][36 * (l15 >> 3) + 4 * (l15 & 7)];
  const float* const frp = &fwb[w][36 * hxl + 8 * q + r];

  // ---- z0 (lanes 0..15 of each wave)
  float z = 0.0f;
  if (lane < 16) {
    const float* cb = coeffs + (size_t)(row0 + r) * (LM1 * 32);
    float x0[8];
    #pragma unroll
    for (int c = 0; c < 8; ++c) x0[c] = cb[c];
    float acc = bi2[hxo];
    for (int j = 0; j < 20; ++j) {
      float u = bi1[j];
      #pragma unroll
      for (int c = 0; c < 8; ++c) u += x0[c] * Wi1[c * 20 + j];
      acc += fmaxf(u, 0.0f) * Wi2[j * 64 + hxo];
    }
    z = fast_tanh(acc);
    out[(size_t)(row0 + r) * 8192 + hxo] = z;
  }

  // ---- per-lane dXdt coeff pipeline: row r, channels 2q / 2q+1
  const float* const gbase = coeffs + (size_t)(row0 + r) * (LM1 * 32);
  const int c0 = 2 * q, c1 = 2 * q + 1;
  float cb0 = gbase[8 + c0],  cc0 = gbase[16 + c0],  cd0 = gbase[24 + c0];
  float cb1 = gbase[8 + c1],  cc1 = gbase[16 + c1],  cd1 = gbase[24 + c1];
  float nb0 = gbase[32 + 8 + c0], nc0 = gbase[32 + 16 + c0], nd0 = gbase[32 + 24 + c0];
  float nb1 = gbase[32 + 8 + c1], nc1 = gbase[32 + 16 + c1], nd1 = gbase[32 + 24 + c1];

  __syncthreads();   // weight staging / first zsb writes ordering

  for (int i = 0; i < LM1; ++i) {
    // g[gi] for this lane's two channels, stage i (registers, no LDS)
    float g0_[3], g1_[3];
    g0_[0] = cb0; g0_[1] = cb0 + cc0 + 0.75f * cd0;
    g0_[2] = (i < LM1 - 1) ? nb0 : fmaf(3.0f, cd0, fmaf(2.0f, cc0, cb0));
    g1_[0] = cb1; g1_[1] = cb1 + cc1 + 0.75f * cd1;
    g1_[2] = (i < LM1 - 1) ? nb1 : fmaf(3.0f, cd1, fmaf(2.0f, cc1, cb1));
    // shift pipeline, issue next-next loads (ready next stage; L2-resident)
    cb0 = nb0; cc0 = nc0; cd0 = nd0;
    cb1 = nb1; cc1 = nc1; cd1 = nd1;
    {
      const int i2 = (i + 2 < LM1) ? (i + 2) : (LM1 - 1);
      const float* nb = gbase + (size_t)i2 * 32;
      nb0 = nb[8 + c0]; nc0 = nb[16 + c0]; nd0 = nb[24 + c0];
      nb1 = nb[8 + c1]; nc1 = nb[16 + c1]; nd1 = nb[24 + c1];
    }

    float ksum = 0.0f, kprev = 0.0f;
    #pragma unroll
    for (int s = 0; s < 4; ++s) {
      const float coef = (s == 0) ? 0.0f : (s == 3) ? 1.0f : 0.5f;
      const float ts   = (float)i + ((s == 0) ? 0.0f : (s == 3) ? 1.0f : 0.5f);
      const int   gi   = (s == 0) ? 0 : (s == 3) ? 2 : 1;

      // Phase A: owners stage zs (16-lane b16)
      if (lane < 16) *zwp = (_Float16)(z + coef * kprev);
      __syncthreads();

      // Phase B: waves 0..7; A-reads masked to the 4 real rows
      if (w < 8) {
        half8_t a0 = {}, a1 = {};
        if (l15 < 4) {
          a0 = *(const half8_t*)(zsb + 8 * (4 * lq + l15));
          a1 = *(const half8_t*)(zsb + 128 + 8 * (4 * lq + l15));
        }
        f32x4 hd = {0.f, 0.f, 0.f, 0.f};
        hd = __builtin_amdgcn_mfma_f32_16x16x32_f16(a0, bB[0], hd, 0, 0, 0);
        hd = __builtin_amdgcn_mfma_f32_16x16x32_f16(a1, bB[1], hd, 0, 0, 0);
        if (lane < 16) {
          const float hb = fmaf(ts, w1t_c, b1_c);
          hwp[0]  = (_Float16)fmaxf(hd.x + hb, 0.0f);
          hwp[8]  = (_Float16)fmaxf(hd.y + hb, 0.0f);
          hwp[16] = (_Float16)fmaxf(hd.z + hb, 0.0f);
          hwp[24] = (_Float16)fmaxf(hd.w + hb, 0.0f);
        }
      }
      __syncthreads();

      // Phase C: wave w -> f-cols [32w,32w+32); A-reads masked to 4 rows
      {
        half8_t ha[4] = {{}, {}, {}, {}};
        if (l15 < 4) {
          #pragma unroll
          for (int kt = 0; kt < 4; ++kt)
            ha[kt] = *(const half8_t*)(hA + kt * 128 + lq * 32 + l15 * 8);
        }
        f32x4 d0 = {0.f, 0.f, 0.f, 0.f}, d1 = d0;
        #pragma unroll
        for (int kt = 0; kt < 4; ++kt) {
          d0 = __builtin_amdgcn_mfma_f32_16x16x32_f16(ha[kt], bf[0][kt], d0, 0, 0, 0);
          d1 = __builtin_amdgcn_mfma_f32_16x16x32_f16(ha[kt], bf[1][kt], d1, 0, 0, 0);
        }
        if (lane < 16) {
          *(f32x4*)(fsp)      = d0;   // cols l15,    rows 0..3
          *(f32x4*)(fsp + 72) = d1;   // cols 16+l15
        }
      }
      asm volatile("s_waitcnt lgkmcnt(0)" ::: "memory");  // within-wave handoff

      // kc: 2 channels/lane, butterfly; finalists lanes 0..15
      {
        const float v0 = frp[0], v1 = frp[4];
        float kcv = fast_tanh(v0 + b2r0) * g0_[gi] + fast_tanh(v1 + b2r1) * g1_[gi];
        kcv += __shfl_xor(kcv, 16, 64);
        kcv += __shfl_xor(kcv, 32, 64);
        kprev = kcv;
        ksum += ((s == 1 || s == 2) ? 2.0f : 1.0f) * kcv;
      }
    }
    if (lane < 16) {
      z += ksum * (1.0f / 6.0f);
      out[(size_t)(row0 + r) * 8192 + (size_t)(i + 1) * 64 + hxo] = z;
    }
  }
}

extern "C" void kernel_launch(void* const* d_in, const int* in_sizes, int n_in,
                              void* d_out, int out_size, void* d_ws, size_t ws_size,
                              hipStream_t stream) {
  const float* coeffs = (const float*)d_in[0];
  const float* Wi1    = (const float*)d_in[1];
  const float* bi1    = (const float*)d_in[2];
  const float* Wi2    = (const float*)d_in[3];
  const float* bi2    = (const float*)d_in[4];
  const float* W1     = (const float*)d_in[5];
  const float* b1     = (const float*)d_in[6];
  const float* W2     = (const float*)d_in[7];
  const float* b2     = (const float*)d_in[8];
  float* out          = (float*)d_out;
  (void)in_sizes; (void)n_in; (void)out_size; (void)d_ws; (void)ws_size;
  cde_kernel<<<256, NTHR, 0, stream>>>(coeffs, Wi1, bi1, Wi2, bi2,
                                       W1, b1, W2, b2, out);
}

// Round 6
// 675.831 us; speedup vs baseline: 1.0002x; 1.0002x over previous
//
#include <hip/hip_runtime.h>
#include <stdint.h>

#define LM1  127
#define NTHR 768

typedef _Float16 half8_t __attribute__((ext_vector_type(8)));
typedef float    f32x4   __attribute__((ext_vector_type(4)));

__device__ __forceinline__ float fast_tanh(float x) {
  float e = __expf(2.0f * x);
  return 1.0f - 2.0f * __builtin_amdgcn_rcpf(e + 1.0f);
}

// 256 blocks x 4 rows x 12 waves (3/SIMD). Wave specialization:
//   waves 0..3  = B-waves: h = relu(zs@W1+..)  (2 n-tiles each, 4 MFMA)
//   waves 4..11 = C-waves: f = h@W2 (4 n-tiles each, 16 MFMA) + tanh/kc +
//                 z-ownership (lanes 0..31: r=lane&3, hx=8wc+4q+h')
// Consolidation halves the dominant ds_read_b128 count vs R4 (64->32).
// dXdt g in registers via pipelined f32x4 loads (wave-uniform guards only —
// R5's per-lane exec-masking regression is avoided). hA padded per lq-block.
__global__ void __launch_bounds__(NTHR, 3) cde_kernel(
    const float* __restrict__ coeffs,
    const float* __restrict__ Wi1, const float* __restrict__ bi1,
    const float* __restrict__ Wi2, const float* __restrict__ bi2,
    const float* __restrict__ W1,  const float* __restrict__ b1,
    const float* __restrict__ W2,  const float* __restrict__ b2,
    float* __restrict__ out)
{
  __shared__ _Float16 zsb[1024];    // A-layout, chunk=kh*64+lq*16+m, read 8*lane+512*kh
  __shared__ _Float16 hA [2176];    // A-layout padded: addr = kt*544 + lq*136 + m*8 + j
  __shared__ float    fwb[8][284];  // per-C-wave D: word = 4*cl + 4*(cl>>3) + m

  const int t    = threadIdx.x;
  const int lane = t & 63;
  const int w    = t >> 6;          // 0..11
  const int l15  = lane & 15;
  const int lq   = lane >> 4;       // 0..3
  const int r    = lane & 3;
  const int row0 = blockIdx.x * 4;
  const int wc   = w - 4;           // C-wave index 0..7 (valid w>=4)

  // zero A-layout buffers once (rows 4..15 + pads stay zero forever)
  for (int u = t; u < 512;  u += NTHR) ((uint32_t*)zsb)[u] = 0u;
  for (int u = t; u < 1088; u += NTHR) ((uint32_t*)hA)[u]  = 0u;

  // ---- B-wave setup: W1 B-frags (2 nt x 2 kt) + epilogue consts
  half8_t bB[2][2];
  float w1t_c[2], b1_c[2];
  if (w < 4) {
    #pragma unroll
    for (int nt = 0; nt < 2; ++nt) {
      #pragma unroll
      for (int kt = 0; kt < 2; ++kt)
        #pragma unroll
        for (int j = 0; j < 8; ++j)
          bB[nt][kt][j] = (_Float16)W1[(1 + kt * 32 + lq * 8 + j) * 128 + 32 * w + nt * 16 + l15];
      w1t_c[nt] = W1[32 * w + nt * 16 + l15];
      b1_c[nt]  = b1[32 * w + nt * 16 + l15];
    }
  }

  // ---- C-wave setup
  const int q  = lane >> 4;           // 0..3
  const int hp = (lane >> 2) & 3;     // h'
  const int c0 = 4 * (q >> 1);        // channel group 0..3 or 4..7
  const int hx = 8 * ((wc < 0) ? 0 : wc) + 4 * (q & 1) + hp;
  half8_t bf[4][4];
  float b2r[4];
  f32x4 pb = {}, pc = {}, pd = {};
  const float* grow = coeffs + (size_t)(row0 + r) * (LM1 * 32);
  if (w >= 4) {
    #pragma unroll
    for (int nt = 0; nt < 4; ++nt)
      #pragma unroll
      for (int kt = 0; kt < 4; ++kt)
        #pragma unroll
        for (int j = 0; j < 8; ++j)
          bf[nt][kt][j] = (_Float16)W2[(kt * 32 + lq * 8 + j) * 512 + 64 * wc + nt * 16 + l15];
    #pragma unroll
    for (int cc = 0; cc < 4; ++cc) b2r[cc] = b2[hx * 8 + c0 + cc];
    pb = *(const f32x4*)(grow + 8 + c0);
    pc = *(const f32x4*)(grow + 16 + c0);
    pd = *(const f32x4*)(grow + 24 + c0);
  }

  // owner constants (C-waves, lanes 0..31): owns (r, hx)
  const bool owner = (w >= 4) && (lane < 32);
  _Float16* const zwp = &zsb[(hx >> 5) * 512 + ((hx >> 3) & 3) * 128 + r * 8 + (hx & 7)];
  const int ha_off = lq * 136 + l15 * 8;                    // phase-C A-read base (halves)
  const int kbase  = 144 * (q & 1) + 36 * hp + 16 * (q >> 1) + r;  // kc read base (words)

  // ---- z0 (owners)
  float z = 0.0f;
  if (owner) {
    float x0[8];
    #pragma unroll
    for (int c = 0; c < 8; ++c) x0[c] = grow[c - 0] ;      // a-channels of l=0 for row r
    // note: grow points at row (row0+r), l=0, offset 0..7 = 'a'
    float acc = bi2[hx];
    for (int j = 0; j < 20; ++j) {
      float u = bi1[j];
      #pragma unroll
      for (int c = 0; c < 8; ++c) u += x0[c] * Wi1[c * 20 + j];
      acc += fmaxf(u, 0.0f) * Wi2[j * 64 + hx];
    }
    z = fast_tanh(acc);
    out[(size_t)(row0 + r) * 8192 + hx] = z;
  }

  __syncthreads();   // zero-init complete before first zsb write/read

  for (int i = 0; i < LM1; ++i) {
    f32x4 g0 = {}, g1 = {}, g2 = {};
    if (w >= 4) {
      g0 = pb;
      g1 = pb + pc + 0.75f * pd;
      const f32x4 glast = pb + 2.0f * pc + 3.0f * pd;
      const float* np = grow + (size_t)((i + 1 < LM1) ? i + 1 : LM1 - 1) * 32;
      pb = *(const f32x4*)(np + 8 + c0);
      pc = *(const f32x4*)(np + 16 + c0);
      pd = *(const f32x4*)(np + 24 + c0);
      g2 = (i < LM1 - 1) ? pb : glast;
    }

    float ksum = 0.0f, kprev = 0.0f;
    #pragma unroll
    for (int s = 0; s < 4; ++s) {
      const float coef = (s == 0) ? 0.0f : (s == 3) ? 1.0f : 0.5f;
      const float ts   = (float)i + ((s == 0) ? 0.0f : (s == 3) ? 1.0f : 0.5f);

      // Phase A: owners stage zs
      if (owner) *zwp = (_Float16)(z + coef * kprev);
      __syncthreads();

      // Phase B: waves 0..3, 2 n-tiles each
      if (w < 4) {
        const half8_t a0 = *(const half8_t*)(zsb + 8 * lane);
        const half8_t a1 = *(const half8_t*)(zsb + 512 + 8 * lane);
        #pragma unroll
        for (int nt = 0; nt < 2; ++nt) {
          f32x4 hd = {0.f, 0.f, 0.f, 0.f};
          hd = __builtin_amdgcn_mfma_f32_16x16x32_f16(a0, bB[nt][0], hd, 0, 0, 0);
          hd = __builtin_amdgcn_mfma_f32_16x16x32_f16(a1, bB[nt][1], hd, 0, 0, 0);
          if (lane < 16) {
            const float hb = fmaf(ts, w1t_c[nt], b1_c[nt]);
            _Float16* hw = &hA[w * 544 + (2 * nt + (l15 >> 3)) * 136 + (l15 & 7)];
            hw[0]  = (_Float16)fmaxf(hd.x + hb, 0.0f);
            hw[8]  = (_Float16)fmaxf(hd.y + hb, 0.0f);
            hw[16] = (_Float16)fmaxf(hd.z + hb, 0.0f);
            hw[24] = (_Float16)fmaxf(hd.w + hb, 0.0f);
          }
        }
      }
      __syncthreads();

      // Phase C + kc: waves 4..11
      if (w >= 4) {
        half8_t ha[4];
        #pragma unroll
        for (int kt = 0; kt < 4; ++kt)
          ha[kt] = *(const half8_t*)(hA + kt * 544 + ha_off);
        f32x4 d0 = {0.f, 0.f, 0.f, 0.f}, d1 = d0, d2 = d0, d3 = d0;
        #pragma unroll
        for (int kt = 0; kt < 4; ++kt) {
          d0 = __builtin_amdgcn_mfma_f32_16x16x32_f16(ha[kt], bf[0][kt], d0, 0, 0, 0);
          d1 = __builtin_amdgcn_mfma_f32_16x16x32_f16(ha[kt], bf[1][kt], d1, 0, 0, 0);
          d2 = __builtin_amdgcn_mfma_f32_16x16x32_f16(ha[kt], bf[2][kt], d2, 0, 0, 0);
          d3 = __builtin_amdgcn_mfma_f32_16x16x32_f16(ha[kt], bf[3][kt], d3, 0, 0, 0);
        }
        if (lane < 16) {
          f32x4 dd[4] = {d0, d1, d2, d3};
          #pragma unroll
          for (int nt = 0; nt < 4; ++nt)
            *(f32x4*)(&fwb[wc][72 * nt + 4 * l15 + 4 * (l15 >> 3)]) = dd[nt];
        }
        asm volatile("s_waitcnt lgkmcnt(0)" ::: "memory");  // in-wave handoff

        const f32x4 gg = (s == 0) ? g0 : (s == 3) ? g2 : g1;
        const float* fp = &fwb[wc][kbase];
        float kcv = fast_tanh(fp[0]  + b2r[0]) * gg.x
                  + fast_tanh(fp[4]  + b2r[1]) * gg.y
                  + fast_tanh(fp[8]  + b2r[2]) * gg.z
                  + fast_tanh(fp[12] + b2r[3]) * gg.w;
        kcv += __shfl_xor(kcv, 32, 64);
        kprev = kcv;
        ksum += ((s == 1 || s == 2) ? 2.0f : 1.0f) * kcv;
      }
    }
    if (owner) {
      z += ksum * (1.0f / 6.0f);
      out[(size_t)(row0 + r) * 8192 + (size_t)(i + 1) * 64 + hx] = z;
    }
  }
}

extern "C" void kernel_launch(void* const* d_in, const int* in_sizes, int n_in,
                              void* d_out, int out_size, void* d_ws, size_t ws_size,
                              hipStream_t stream) {
  const float* coeffs = (const float*)d_in[0];
  const float* Wi1    = (const float*)d_in[1];
  const float* bi1    = (const float*)d_in[2];
  const float* Wi2    = (const float*)d_in[3];
  const float* bi2    = (const float*)d_in[4];
  const float* W1     = (const float*)d_in[5];
  const float* b1     = (const float*)d_in[6];
  const float* W2     = (const float*)d_in[7];
  const float* b2     = (const float*)d_in[8];
  float* out          = (float*)d_out;
  (void)in_sizes; (void)n_in; (void)out_size; (void)d_ws; (void)ws_size;
  cde_kernel<<<256, NTHR, 0, stream>>>(coeffs, Wi1, bi1, Wi2, bi2,
                                       W1, b1, W2, b2, out);
}